// Round 1
// baseline (1332.523 us; speedup 1.0000x reference)
//
#include <hip/hip_runtime.h>

#define NN 100000
#define EE 1600000
#define FIN 1024
#define HH 128
#define OUTD 32
#define TOTC 10000.0f

typedef float f32x4 __attribute__((ext_vector_type(4)));
typedef short bf16x8 __attribute__((ext_vector_type(8)));
typedef short short4v __attribute__((ext_vector_type(4)));

static __device__ __forceinline__ short f2bf(float f) {
    unsigned u = __float_as_uint(f);
    unsigned r = (u + 0x7fffu + ((u >> 16) & 1u)) >> 16;
    return (short)r;
}

// ---------------- small utility kernels ----------------
__global__ void zero_k(int* __restrict__ p, int n) {
    int i = blockIdx.x * 256 + threadIdx.x;
    if (i < n) p[i] = 0;
}

// row sums of x -> l (output #2), one block per row
__global__ __launch_bounds__(256) void rowsum_k(const float* __restrict__ x,
                                                float* __restrict__ lout) {
    int row = blockIdx.x;
    int tid = threadIdx.x;
    const float4* px = (const float4*)(x + (long)row * FIN);
    float4 v = px[tid];
    float s = v.x + v.y + v.z + v.w;
#pragma unroll
    for (int o = 32; o; o >>= 1) s += __shfl_xor(s, o);
    __shared__ float ws[4];
    if ((tid & 63) == 0) ws[tid >> 6] = s;
    __syncthreads();
    if (tid == 0) lout[row] = ws[0] + ws[1] + ws[2] + ws[3];
}

// weight conversions (bf16, transposed: BT[n][k] = W[k][n])
__global__ void convW0_k(const float* __restrict__ W, short* __restrict__ BT) {
    int idx = blockIdx.x * 256 + threadIdx.x;     // 128*1024
    int n = idx >> 10, k = idx & 1023;
    BT[idx] = f2bf(W[(long)k * HH + n]);
}
__global__ void convW1_k(const float* __restrict__ W, short* __restrict__ BT) {
    int idx = blockIdx.x * 256 + threadIdx.x;     // 128*128
    int n = idx >> 7, k = idx & 127;
    BT[idx] = f2bf(W[k * HH + n]);
}
__global__ void convWH_k(const float* __restrict__ locW, const float* __restrict__ stdW,
                         short* __restrict__ BT) {
    int idx = blockIdx.x * 256 + threadIdx.x;     // 128*128
    int n = idx >> 7, k = idx & 127;
    float v = (n < 32) ? locW[k * OUTD + n] : ((n < 64) ? stdW[k * OUTD + (n - 32)] : 0.0f);
    BT[idx] = f2bf(v);
}

// ---------------- CSR build ----------------
__global__ void hist_k(const int* __restrict__ dst, int* __restrict__ cnt, int e) {
    int i = blockIdx.x * 256 + threadIdx.x;
    if (i < e) atomicAdd(cnt + dst[i], 1);
}

__global__ __launch_bounds__(256) void scanA_k(const int* __restrict__ cnt,
                                               int* __restrict__ out,
                                               int* __restrict__ partials, int n) {
    __shared__ int sc[256];
    int tid = threadIdx.x;
    int base = blockIdx.x * 1024 + tid * 4;
    int c[4];
#pragma unroll
    for (int u = 0; u < 4; u++) c[u] = (base + u < n) ? cnt[base + u] : 0;
    int s = c[0] + c[1] + c[2] + c[3];
    sc[tid] = s;
    __syncthreads();
    for (int of = 1; of < 256; of <<= 1) {
        int v = (tid >= of) ? sc[tid - of] : 0;
        __syncthreads();
        sc[tid] += v;
        __syncthreads();
    }
    int e = sc[tid] - s;
#pragma unroll
    for (int u = 0; u < 4; u++) {
        if (base + u < n) out[base + u] = e;
        e += c[u];
    }
    if (tid == 255) partials[blockIdx.x] = sc[255];
}

__global__ __launch_bounds__(128) void scanB_k(int* __restrict__ partials, int nblk) {
    __shared__ int sc[128];
    int tid = threadIdx.x;
    int v = (tid < nblk) ? partials[tid] : 0;
    sc[tid] = v;
    __syncthreads();
    for (int of = 1; of < 128; of <<= 1) {
        int t2 = (tid >= of) ? sc[tid - of] : 0;
        __syncthreads();
        sc[tid] += t2;
        __syncthreads();
    }
    if (tid < nblk) partials[tid] = sc[tid] - v;   // exclusive block offsets
}

__global__ void scanC_k(int* __restrict__ rp, const int* __restrict__ offs, int n, int total) {
    int i = blockIdx.x * 256 + threadIdx.x;
    if (i < n) rp[i] += offs[i >> 10];
    if (i == 0) rp[n] = total;
}

__global__ void fill_k(const int* __restrict__ src, const int* __restrict__ dst,
                       const int* __restrict__ rp, int* __restrict__ cur,
                       int* __restrict__ cs, int e) {
    int i = blockIdx.x * 256 + threadIdx.x;
    if (i < e) {
        int d = dst[i];
        int p = atomicAdd(cur + d, 1);
        cs[rp[d] + p] = src[i];
    }
}

// ---------------- bf16 MFMA GEMM: C[M,128] = A[M,K] @ B[K,128] ----------------
// ASRC: 0 = A is fp32 x with fused log1p(x * TOTC/l[row]); 1 = A is bf16 (shorts)
// EPI:  0 = store fp32 C; 1 = head epilogue (loc + softplus(std))
#define LDP 88   // padded LDS row stride in bf16 elems (176 B, 16B-divisible)

template <int ASRC, int EPI>
__global__ __launch_bounds__(256) void gemm_k(
    const void* __restrict__ Ap, const float* __restrict__ lvec,
    const short* __restrict__ BT, float* __restrict__ C,
    const float* __restrict__ bias_loc, const float* __restrict__ bias_std,
    float* __restrict__ out_loc, float* __restrict__ out_std, int M, int K) {
    __shared__ short sA[128 * LDP];
    __shared__ short sB[128 * LDP];
    __shared__ float sScale[128];
    const int tid = threadIdx.x;
    const int row0 = blockIdx.x * 128;
    if (ASRC == 0) {
        if (tid < 128) {
            int g = row0 + tid;
            sScale[tid] = (g < M) ? (TOTC / lvec[g]) : 0.0f;
        }
    }
    __syncthreads();

    const int lane = tid & 63;
    const int wv = tid >> 6;
    const int wm = (wv & 1) * 64, wn = (wv >> 1) * 64;
    const int lm = lane & 15, q = lane >> 4;

    f32x4 acc[4][4];
#pragma unroll
    for (int i = 0; i < 4; i++)
#pragma unroll
        for (int j = 0; j < 4; j++) acc[i][j] = {0.f, 0.f, 0.f, 0.f};

    const int r = tid >> 1;            // 0..127 (tile row / B col)
    const int cb = (tid & 1) * 32;     // k-chunk base within BK=64
    const int gr = row0 + r;

    for (int kk = 0; kk < K; kk += 64) {
        // ---- stage A tile [128 x 64] ----
        if (ASRC == 0) {
            const float* X = (const float*)Ap;
            const float s = sScale[r];
            if (gr < M) {
                const float4* px = (const float4*)(X + (long)gr * K + kk + cb);
#pragma unroll
                for (int u = 0; u < 8; ++u) {
                    float4 v = px[u];
                    short4v o;
                    o.x = f2bf(__logf(fmaf(v.x, s, 1.0f)));
                    o.y = f2bf(__logf(fmaf(v.y, s, 1.0f)));
                    o.z = f2bf(__logf(fmaf(v.z, s, 1.0f)));
                    o.w = f2bf(__logf(fmaf(v.w, s, 1.0f)));
                    *(short4v*)&sA[r * LDP + cb + u * 4] = o;
                }
            } else {
                short4v z;
                z.x = z.y = z.z = z.w = 0;
#pragma unroll
                for (int u = 0; u < 8; ++u) *(short4v*)&sA[r * LDP + cb + u * 4] = z;
            }
        } else {
            const short* A = (const short*)Ap;
            if (gr < M) {
                const short4v* pa = (const short4v*)(A + (long)gr * K + kk + cb);
#pragma unroll
                for (int u = 0; u < 8; ++u) *(short4v*)&sA[r * LDP + cb + u * 4] = pa[u];
            } else {
                short4v z;
                z.x = z.y = z.z = z.w = 0;
#pragma unroll
                for (int u = 0; u < 8; ++u) *(short4v*)&sA[r * LDP + cb + u * 4] = z;
            }
        }
        // ---- stage B tile: sB[n][k] from BT[n][K] ----
        {
            const short4v* pb = (const short4v*)(BT + (long)r * K + kk + cb);
#pragma unroll
            for (int u = 0; u < 8; ++u) *(short4v*)&sB[r * LDP + cb + u * 4] = pb[u];
        }
        __syncthreads();
        // ---- MFMA: 2 k-steps of 32 ----
#pragma unroll
        for (int ks = 0; ks < 64; ks += 32) {
            bf16x8 af[4], bf[4];
#pragma unroll
            for (int i = 0; i < 4; i++)
                af[i] = *(const bf16x8*)&sA[(wm + i * 16 + lm) * LDP + ks + q * 8];
#pragma unroll
            for (int j = 0; j < 4; j++)
                bf[j] = *(const bf16x8*)&sB[(wn + j * 16 + lm) * LDP + ks + q * 8];
#pragma unroll
            for (int i = 0; i < 4; i++)
#pragma unroll
                for (int j = 0; j < 4; j++)
                    acc[i][j] = __builtin_amdgcn_mfma_f32_16x16x32_bf16(af[i], bf[j], acc[i][j], 0, 0, 0);
        }
        __syncthreads();
    }

    // ---- epilogue ----
    if (EPI == 0) {
#pragma unroll
        for (int i = 0; i < 4; i++)
#pragma unroll
            for (int rg = 0; rg < 4; rg++) {
                int grow = row0 + wm + i * 16 + q * 4 + rg;
                if (grow < M) {
#pragma unroll
                    for (int j = 0; j < 4; j++) {
                        int col = wn + j * 16 + lm;
                        C[(long)grow * HH + col] = acc[i][j][rg];
                    }
                }
            }
    } else {
        if (wn == 0) {
#pragma unroll
            for (int i = 0; i < 4; i++)
#pragma unroll
                for (int rg = 0; rg < 4; rg++) {
                    int grow = row0 + wm + i * 16 + q * 4 + rg;
                    if (grow < M) {
#pragma unroll
                        for (int j = 0; j < 4; j++) {
                            int col = j * 16 + lm;   // 0..63
                            float v = acc[i][j][rg];
                            if (col < 32) {
                                out_loc[(long)grow * OUTD + col] = v + bias_loc[col];
                            } else {
                                float xv = v + bias_std[col - 32];
                                float sp = fmaxf(xv, 0.f) + __logf(1.f + __expf(-fabsf(xv)));
                                out_std[(long)grow * OUTD + (col - 32)] = sp + 1e-7f;
                            }
                        }
                    }
                }
        }
    }
}

// ---------------- alpha: per-row dots with a_s / a_d ----------------
__global__ __launch_bounds__(256) void alpha_k(const float* __restrict__ h2,
                                               const float* __restrict__ avs,
                                               const float* __restrict__ avd,
                                               float* __restrict__ outs,
                                               float* __restrict__ outd, int n) {
    int lane = threadIdx.x & 63;
    int row = blockIdx.x * 4 + (threadIdx.x >> 6);
    if (row >= n) return;
    float2 v = *(const float2*)(h2 + (long)row * HH + 2 * lane);
    float ps = v.x * avs[2 * lane] + v.y * avs[2 * lane + 1];
    float pd = v.x * avd[2 * lane] + v.y * avd[2 * lane + 1];
#pragma unroll
    for (int o = 32; o; o >>= 1) {
        ps += __shfl_xor(ps, o);
        pd += __shfl_xor(pd, o);
    }
    if (lane == 0) {
        outs[row] = ps;
        outd[row] = pd;
    }
}

// ---------------- GAT aggregation: one wave per dst node ----------------
__global__ __launch_bounds__(256) void agg_k(const float* __restrict__ h2,
                                             const float* __restrict__ as,
                                             const float* __restrict__ ad,
                                             const int* __restrict__ row_ptr,
                                             const int* __restrict__ col_src,
                                             float* __restrict__ out, int n) {
    int lane = threadIdx.x & 63;
    int node = blockIdx.x * 4 + (threadIdx.x >> 6);
    if (node >= n) return;
    int s0 = row_ptr[node], s1 = row_ptr[node + 1];
    float adv = ad[node];
    float m = -INFINITY;
    for (int b = s0; b < s1; b += 64) {
        int idx = b + lane;
        if (idx < s1) {
            float e = as[col_src[idx]] + adv;
            e = (e > 0.f) ? e : 0.2f * e;
            m = fmaxf(m, e);
        }
    }
#pragma unroll
    for (int o = 32; o; o >>= 1) m = fmaxf(m, __shfl_xor(m, o));

    float acc0 = 0.f, acc1 = 0.f, wsum = 0.f;
    for (int b = s0; b < s1; b += 64) {
        int idx = b + lane;
        int cl = min(64, s1 - b);
        float w = 0.f;
        int s = 0;
        if (idx < s1) {
            s = col_src[idx];
            float e = as[s] + adv;
            e = (e > 0.f) ? e : 0.2f * e;
            w = __expf(e - m);
            wsum += w;
        }
        for (int j = 0; j < cl; ++j) {
            float wj = __shfl(w, j);
            int sj = __shfl(s, j);
            float2 hv = *(const float2*)(h2 + (long)sj * HH + 2 * lane);
            acc0 = fmaf(wj, hv.x, acc0);
            acc1 = fmaf(wj, hv.y, acc1);
        }
    }
#pragma unroll
    for (int o = 32; o; o >>= 1) wsum += __shfl_xor(wsum, o);
    float inv = 1.f / (wsum + 1e-16f);
    float2 o2;
    o2.x = acc0 * inv;
    o2.y = acc1 * inv;
    *(float2*)(out + (long)node * HH + 2 * lane) = o2;
}

// ---------------- batchnorm ----------------
__global__ __launch_bounds__(256) void bnstats_k(const float* __restrict__ h,
                                                 float* __restrict__ bsum,
                                                 float* __restrict__ bsq, int n) {
    int col = threadIdx.x & 127;
    int half = threadIdx.x >> 7;
    int stride = gridDim.x * 2;
    float s = 0.f, sq = 0.f;
    for (int row = blockIdx.x * 2 + half; row < n; row += stride) {
        float v = h[(long)row * HH + col];
        s += v;
        sq += v * v;
    }
    atomicAdd(bsum + col, s);
    atomicAdd(bsq + col, sq);
}

__global__ __launch_bounds__(256) void bnapply_k(const float* __restrict__ h,
                                                 const float* __restrict__ bsum,
                                                 const float* __restrict__ bsq,
                                                 const float* __restrict__ g,
                                                 const float* __restrict__ b,
                                                 short* __restrict__ obf, int n) {
    long idx = (long)blockIdx.x * 256 + threadIdx.x;   // one float4 (4 cols) per thread
    long total = (long)n * 32;
    if (idx >= total) return;
    int col0 = ((int)(idx & 31)) * 4;
    float4 v = *(const float4*)(h + idx * 4);
    const float invn = 1.0f / (float)n;
    short4v o;
    float vv[4] = {v.x, v.y, v.z, v.w};
    short oo[4];
#pragma unroll
    for (int j = 0; j < 4; j++) {
        int c = col0 + j;
        float mu = bsum[c] * invn;
        float var = bsq[c] * invn - mu * mu;
        float rs = rsqrtf(var + 1e-5f);
        float val = (vv[j] - mu) * rs * g[c] + b[c];
        val = (val > 0.f) ? val : 0.2f * val;
        oo[j] = f2bf(val);
    }
    o.x = oo[0]; o.y = oo[1]; o.z = oo[2]; o.w = oo[3];
    *(short4v*)(obf + idx * 4) = o;
}

// ---------------- launch ----------------
extern "C" void kernel_launch(void* const* d_in, const int* in_sizes, int n_in,
                              void* d_out, int out_size, void* d_ws, size_t ws_size,
                              hipStream_t stream) {
    const float* x = (const float*)d_in[0];
    const int* ei = (const int*)d_in[1];
    const int* srcp = ei;
    const int* dstp = ei + EE;
    const float* W0 = (const float*)d_in[2];
    const float* as0 = (const float*)d_in[3];
    const float* ad0 = (const float*)d_in[4];
    const float* g0 = (const float*)d_in[5];
    const float* b0 = (const float*)d_in[6];
    const float* W1 = (const float*)d_in[7];
    const float* as1 = (const float*)d_in[8];
    const float* ad1 = (const float*)d_in[9];
    const float* g1 = (const float*)d_in[10];
    const float* b1 = (const float*)d_in[11];
    const float* locW = (const float*)d_in[12];
    const float* locb = (const float*)d_in[13];
    const float* stdW = (const float*)d_in[14];
    const float* stdb = (const float*)d_in[15];

    float* out = (float*)d_out;
    float* out_loc = out;
    float* out_std = out + (long)NN * OUTD;
    float* lvec = out + 2L * NN * OUTD;

    char* wsb = (char*)d_ws;
    size_t off = 0;
    auto alloc = [&](size_t bytes) {
        size_t cur = off;
        off += (bytes + 255) & ~(size_t)255;
        return cur;
    };
    float* h2 = (float*)(wsb + alloc((size_t)NN * HH * 4));
    float* h_agg = (float*)(wsb + alloc((size_t)NN * HH * 4));
    short* ptrbf = (short*)(wsb + alloc((size_t)NN * HH * 2));
    int* col_src = (int*)(wsb + alloc((size_t)EE * 4));
    int* zreg = (int*)(wsb + alloc((size_t)(2 * NN + 256) * 4));  // counts|cursor|bn
    int* counts = zreg;
    int* cursor = zreg + NN;
    float* bn_sum = (float*)(zreg + 2 * NN);
    float* bn_sq = bn_sum + 128;
    int* row_ptr = (int*)(wsb + alloc((size_t)(NN + 1) * 4));
    float* alpha_s = (float*)(wsb + alloc((size_t)NN * 4));
    float* alpha_d = (float*)(wsb + alloc((size_t)NN * 4));
    short* W0T = (short*)(wsb + alloc((size_t)HH * FIN * 2));
    short* W1T = (short*)(wsb + alloc((size_t)HH * HH * 2));
    short* WHT = (short*)(wsb + alloc((size_t)HH * HH * 2));
    int* partials = (int*)(wsb + alloc(512));

    const int ZN = 2 * NN + 256;
    zero_k<<<(ZN + 255) / 256, 256, 0, stream>>>(zreg, ZN);
    convW0_k<<<(HH * FIN) / 256, 256, 0, stream>>>(W0, W0T);
    convW1_k<<<(HH * HH) / 256, 256, 0, stream>>>(W1, W1T);
    convWH_k<<<(HH * HH) / 256, 256, 0, stream>>>(locW, stdW, WHT);
    rowsum_k<<<NN, 256, 0, stream>>>(x, lvec);

    hist_k<<<(EE + 255) / 256, 256, 0, stream>>>(dstp, counts, EE);
    scanA_k<<<(NN + 1023) / 1024, 256, 0, stream>>>(counts, row_ptr, partials, NN);
    scanB_k<<<1, 128, 0, stream>>>(partials, (NN + 1023) / 1024);
    scanC_k<<<(NN + 255) / 256, 256, 0, stream>>>(row_ptr, partials, NN, EE);
    fill_k<<<(EE + 255) / 256, 256, 0, stream>>>(srcp, dstp, row_ptr, cursor, col_src, EE);

    const int GB = (NN + 127) / 128;   // 782 gemm blocks
    // ---- layer 0 ----
    gemm_k<0, 0><<<GB, 256, 0, stream>>>(x, lvec, W0T, h2, nullptr, nullptr, nullptr, nullptr, NN, FIN);
    alpha_k<<<(NN + 3) / 4, 256, 0, stream>>>(h2, as0, ad0, alpha_s, alpha_d, NN);
    agg_k<<<(NN + 3) / 4, 256, 0, stream>>>(h2, alpha_s, alpha_d, row_ptr, col_src, h_agg, NN);
    bnstats_k<<<256, 256, 0, stream>>>(h_agg, bn_sum, bn_sq, NN);
    bnapply_k<<<(NN * 32 + 255) / 256, 256, 0, stream>>>(h_agg, bn_sum, bn_sq, g0, b0, ptrbf, NN);
    zero_k<<<1, 256, 0, stream>>>((int*)bn_sum, 256);
    // ---- layer 1 ----
    gemm_k<1, 0><<<GB, 256, 0, stream>>>(ptrbf, nullptr, W1T, h2, nullptr, nullptr, nullptr, nullptr, NN, HH);
    alpha_k<<<(NN + 3) / 4, 256, 0, stream>>>(h2, as1, ad1, alpha_s, alpha_d, NN);
    agg_k<<<(NN + 3) / 4, 256, 0, stream>>>(h2, alpha_s, alpha_d, row_ptr, col_src, h_agg, NN);
    bnstats_k<<<256, 256, 0, stream>>>(h_agg, bn_sum, bn_sq, NN);
    bnapply_k<<<(NN * 32 + 255) / 256, 256, 0, stream>>>(h_agg, bn_sum, bn_sq, g1, b1, ptrbf, NN);
    // ---- head ----
    gemm_k<1, 1><<<GB, 256, 0, stream>>>(ptrbf, nullptr, WHT, nullptr, locb, stdb, out_loc, out_std, NN, HH);
}

// Round 2
// 1205.848 us; speedup vs baseline: 1.1051x; 1.1051x over previous
//
#include <hip/hip_runtime.h>

#define NN 100000
#define EE 1600000
#define FIN 1024
#define HH 128
#define OUTD 32
#define TOTC 10000.0f

typedef float f32x4 __attribute__((ext_vector_type(4)));
typedef short bf16x8 __attribute__((ext_vector_type(8)));
typedef short short4v __attribute__((ext_vector_type(4)));

static __device__ __forceinline__ short f2bf(float f) {
    unsigned u = __float_as_uint(f);
    unsigned r = (u + 0x7fffu + ((u >> 16) & 1u)) >> 16;
    return (short)r;
}
static __device__ __forceinline__ float bf2f(short s) {
    return __uint_as_float(((unsigned)(unsigned short)s) << 16);
}

// ---------------- small utility kernels ----------------
__global__ void zero_k(int* __restrict__ p, int n) {
    int i = blockIdx.x * 256 + threadIdx.x;
    if (i < n) p[i] = 0;
}

// row sums of x -> l (output #2), one block per row
__global__ __launch_bounds__(256) void rowsum_k(const float* __restrict__ x,
                                                float* __restrict__ lout) {
    int row = blockIdx.x;
    int tid = threadIdx.x;
    const float4* px = (const float4*)(x + (long)row * FIN);
    float4 v = px[tid];
    float s = v.x + v.y + v.z + v.w;
#pragma unroll
    for (int o = 32; o; o >>= 1) s += __shfl_xor(s, o);
    __shared__ float ws[4];
    if ((tid & 63) == 0) ws[tid >> 6] = s;
    __syncthreads();
    if (tid == 0) lout[row] = ws[0] + ws[1] + ws[2] + ws[3];
}

// weight conversions (bf16, transposed: BT[n][k] = W[k][n])
__global__ void convW0_k(const float* __restrict__ W, short* __restrict__ BT) {
    int idx = blockIdx.x * 256 + threadIdx.x;     // 128*1024
    int n = idx >> 10, k = idx & 1023;
    BT[idx] = f2bf(W[(long)k * HH + n]);
}
__global__ void convW1_k(const float* __restrict__ W, short* __restrict__ BT) {
    int idx = blockIdx.x * 256 + threadIdx.x;     // 128*128
    int n = idx >> 7, k = idx & 127;
    BT[idx] = f2bf(W[k * HH + n]);
}
__global__ void convWH_k(const float* __restrict__ locW, const float* __restrict__ stdW,
                         short* __restrict__ BT) {
    int idx = blockIdx.x * 256 + threadIdx.x;     // 128*128
    int n = idx >> 7, k = idx & 127;
    float v = (n < 32) ? locW[k * OUTD + n] : ((n < 64) ? stdW[k * OUTD + (n - 32)] : 0.0f);
    BT[idx] = f2bf(v);
}

// ---------------- CSR build ----------------
__global__ void hist_k(const int* __restrict__ dst, int* __restrict__ cnt, int e) {
    int i = blockIdx.x * 256 + threadIdx.x;
    if (i < e) atomicAdd(cnt + dst[i], 1);
}

__global__ __launch_bounds__(256) void scanA_k(const int* __restrict__ cnt,
                                               int* __restrict__ out,
                                               int* __restrict__ partials, int n) {
    __shared__ int sc[256];
    int tid = threadIdx.x;
    int base = blockIdx.x * 1024 + tid * 4;
    int c[4];
#pragma unroll
    for (int u = 0; u < 4; u++) c[u] = (base + u < n) ? cnt[base + u] : 0;
    int s = c[0] + c[1] + c[2] + c[3];
    sc[tid] = s;
    __syncthreads();
    for (int of = 1; of < 256; of <<= 1) {
        int v = (tid >= of) ? sc[tid - of] : 0;
        __syncthreads();
        sc[tid] += v;
        __syncthreads();
    }
    int e = sc[tid] - s;
#pragma unroll
    for (int u = 0; u < 4; u++) {
        if (base + u < n) out[base + u] = e;
        e += c[u];
    }
    if (tid == 255) partials[blockIdx.x] = sc[255];
}

__global__ __launch_bounds__(128) void scanB_k(int* __restrict__ partials, int nblk) {
    __shared__ int sc[128];
    int tid = threadIdx.x;
    int v = (tid < nblk) ? partials[tid] : 0;
    sc[tid] = v;
    __syncthreads();
    for (int of = 1; of < 128; of <<= 1) {
        int t2 = (tid >= of) ? sc[tid - of] : 0;
        __syncthreads();
        sc[tid] += t2;
        __syncthreads();
    }
    if (tid < nblk) partials[tid] = sc[tid] - v;   // exclusive block offsets
}

__global__ void scanC_k(int* __restrict__ rp, const int* __restrict__ offs, int n, int total) {
    int i = blockIdx.x * 256 + threadIdx.x;
    if (i < n) rp[i] += offs[i >> 10];
    if (i == 0) rp[n] = total;
}

__global__ void fill_k(const int* __restrict__ src, const int* __restrict__ dst,
                       const int* __restrict__ rp, int* __restrict__ cur,
                       int* __restrict__ cs, int e) {
    int i = blockIdx.x * 256 + threadIdx.x;
    if (i < e) {
        int d = dst[i];
        int p = atomicAdd(cur + d, 1);
        cs[rp[d] + p] = src[i];
    }
}

// ---------------- bf16 MFMA GEMM: C[M,128] = A[M,K] @ B[K,128] ----------------
// ASRC: 0 = A is fp32 x with fused log1p(x * TOTC/l[row]); 1 = A is bf16 (shorts)
// EPI:  0 = store bf16 C; 1 = head epilogue (loc + softplus(std))
#define LDP 88   // padded LDS row stride in bf16 elems (176 B, 16B-divisible)

template <int ASRC, int EPI>
__global__ __launch_bounds__(256) void gemm_k(
    const void* __restrict__ Ap, const float* __restrict__ lvec,
    const short* __restrict__ BT, short* __restrict__ Cbf,
    const float* __restrict__ bias_loc, const float* __restrict__ bias_std,
    float* __restrict__ out_loc, float* __restrict__ out_std, int M, int K) {
    __shared__ short sA[128 * LDP];
    __shared__ short sB[128 * LDP];
    __shared__ float sScale[128];
    const int tid = threadIdx.x;
    const int row0 = blockIdx.x * 128;
    if (ASRC == 0) {
        if (tid < 128) {
            int g = row0 + tid;
            sScale[tid] = (g < M) ? (TOTC / lvec[g]) : 0.0f;
        }
    }
    __syncthreads();

    const int lane = tid & 63;
    const int wv = tid >> 6;
    const int wm = (wv & 1) * 64, wn = (wv >> 1) * 64;
    const int lm = lane & 15, q = lane >> 4;

    f32x4 acc[4][4];
#pragma unroll
    for (int i = 0; i < 4; i++)
#pragma unroll
        for (int j = 0; j < 4; j++) acc[i][j] = {0.f, 0.f, 0.f, 0.f};

    const int r = tid >> 1;            // 0..127 (tile row / B col)
    const int cb = (tid & 1) * 32;     // k-chunk base within BK=64
    const int gr = row0 + r;

    for (int kk = 0; kk < K; kk += 64) {
        // ---- stage A tile [128 x 64] ----
        if (ASRC == 0) {
            const float* X = (const float*)Ap;
            const float s = sScale[r];
            if (gr < M) {
                const float4* px = (const float4*)(X + (long)gr * K + kk + cb);
#pragma unroll
                for (int u = 0; u < 8; ++u) {
                    float4 v = px[u];
                    short4v o;
                    o.x = f2bf(__logf(fmaf(v.x, s, 1.0f)));
                    o.y = f2bf(__logf(fmaf(v.y, s, 1.0f)));
                    o.z = f2bf(__logf(fmaf(v.z, s, 1.0f)));
                    o.w = f2bf(__logf(fmaf(v.w, s, 1.0f)));
                    *(short4v*)&sA[r * LDP + cb + u * 4] = o;
                }
            } else {
                short4v z;
                z.x = z.y = z.z = z.w = 0;
#pragma unroll
                for (int u = 0; u < 8; ++u) *(short4v*)&sA[r * LDP + cb + u * 4] = z;
            }
        } else {
            const short* A = (const short*)Ap;
            if (gr < M) {
                const short4v* pa = (const short4v*)(A + (long)gr * K + kk + cb);
#pragma unroll
                for (int u = 0; u < 8; ++u) *(short4v*)&sA[r * LDP + cb + u * 4] = pa[u];
            } else {
                short4v z;
                z.x = z.y = z.z = z.w = 0;
#pragma unroll
                for (int u = 0; u < 8; ++u) *(short4v*)&sA[r * LDP + cb + u * 4] = z;
            }
        }
        // ---- stage B tile: sB[n][k] from BT[n][K] ----
        {
            const short4v* pb = (const short4v*)(BT + (long)r * K + kk + cb);
#pragma unroll
            for (int u = 0; u < 8; ++u) *(short4v*)&sB[r * LDP + cb + u * 4] = pb[u];
        }
        __syncthreads();
        // ---- MFMA: 2 k-steps of 32 ----
#pragma unroll
        for (int ks = 0; ks < 64; ks += 32) {
            bf16x8 af[4], bf[4];
#pragma unroll
            for (int i = 0; i < 4; i++)
                af[i] = *(const bf16x8*)&sA[(wm + i * 16 + lm) * LDP + ks + q * 8];
#pragma unroll
            for (int j = 0; j < 4; j++)
                bf[j] = *(const bf16x8*)&sB[(wn + j * 16 + lm) * LDP + ks + q * 8];
#pragma unroll
            for (int i = 0; i < 4; i++)
#pragma unroll
                for (int j = 0; j < 4; j++)
                    acc[i][j] = __builtin_amdgcn_mfma_f32_16x16x32_bf16(af[i], bf[j], acc[i][j], 0, 0, 0);
        }
        __syncthreads();
    }

    // ---- epilogue ----
    if (EPI == 0) {
#pragma unroll
        for (int i = 0; i < 4; i++)
#pragma unroll
            for (int rg = 0; rg < 4; rg++) {
                int grow = row0 + wm + i * 16 + q * 4 + rg;
                if (grow < M) {
#pragma unroll
                    for (int j = 0; j < 4; j++) {
                        int col = wn + j * 16 + lm;
                        Cbf[(long)grow * HH + col] = f2bf(acc[i][j][rg]);
                    }
                }
            }
    } else {
        if (wn == 0) {
#pragma unroll
            for (int i = 0; i < 4; i++)
#pragma unroll
                for (int rg = 0; rg < 4; rg++) {
                    int grow = row0 + wm + i * 16 + q * 4 + rg;
                    if (grow < M) {
#pragma unroll
                        for (int j = 0; j < 4; j++) {
                            int col = j * 16 + lm;   // 0..63
                            float v = acc[i][j][rg];
                            if (col < 32) {
                                out_loc[(long)grow * OUTD + col] = v + bias_loc[col];
                            } else {
                                float xv = v + bias_std[col - 32];
                                float sp = fmaxf(xv, 0.f) + __logf(1.f + __expf(-fabsf(xv)));
                                out_std[(long)grow * OUTD + (col - 32)] = sp + 1e-7f;
                            }
                        }
                    }
                }
        }
    }
}

// ---------------- alpha: per-row dots with a_s / a_d (bf16 h2) ----------------
__global__ __launch_bounds__(256) void alpha_k(const short* __restrict__ h2bf,
                                               const float* __restrict__ avs,
                                               const float* __restrict__ avd,
                                               float* __restrict__ outs,
                                               float* __restrict__ outd, int n) {
    int lane = threadIdx.x & 63;
    int row = blockIdx.x * 4 + (threadIdx.x >> 6);
    if (row >= n) return;
    unsigned pv = *(const unsigned*)(h2bf + (long)row * HH + 2 * lane);
    float v0 = __uint_as_float((pv & 0xffffu) << 16);
    float v1 = __uint_as_float(pv & 0xffff0000u);
    float ps = v0 * avs[2 * lane] + v1 * avs[2 * lane + 1];
    float pd = v0 * avd[2 * lane] + v1 * avd[2 * lane + 1];
#pragma unroll
    for (int o = 32; o; o >>= 1) {
        ps += __shfl_xor(ps, o);
        pd += __shfl_xor(pd, o);
    }
    if (lane == 0) {
        outs[row] = ps;
        outd[row] = pd;
    }
}

// ---------------- GAT aggregation: one wave per dst node, 4 edges/iter ----------------
__global__ __launch_bounds__(256) void agg_k(const short* __restrict__ h2bf,
                                             const float* __restrict__ as,
                                             const float* __restrict__ ad,
                                             const int* __restrict__ row_ptr,
                                             const int* __restrict__ col_src,
                                             float* __restrict__ out, int n) {
    int lane = threadIdx.x & 63;
    int node = blockIdx.x * 4 + (threadIdx.x >> 6);
    if (node >= n) return;
    int s0 = row_ptr[node], s1 = row_ptr[node + 1];
    float adv = ad[node];
    float m = -INFINITY;
    for (int b = s0; b < s1; b += 64) {
        int idx = b + lane;
        if (idx < s1) {
            float e = as[col_src[idx]] + adv;
            e = (e > 0.f) ? e : 0.2f * e;
            m = fmaxf(m, e);
        }
    }
#pragma unroll
    for (int o = 32; o; o >>= 1) m = fmaxf(m, __shfl_xor(m, o));

    const int eg = lane >> 4;        // edge subgroup 0..3
    const int f8 = (lane & 15) * 8;  // feature octet offset
    float accf[8];
#pragma unroll
    for (int u = 0; u < 8; u++) accf[u] = 0.f;
    float wsum = 0.f;

    for (int b = s0; b < s1; b += 64) {
        int idx = b + lane;
        float w = 0.f;
        int s = 0;
        if (idx < s1) {
            s = col_src[idx];
            float e = as[s] + adv;
            e = (e > 0.f) ? e : 0.2f * e;
            w = __expf(e - m);
            wsum += w;
        }
        int cl = min(64, s1 - b);
        for (int j = eg; j < cl; j += 4) {
            float wj = __shfl(w, j);
            int sj = __shfl(s, j);
            bf16x8 hv = *(const bf16x8*)(h2bf + (long)sj * HH + f8);
#pragma unroll
            for (int u = 0; u < 8; u++)
                accf[u] = fmaf(wj, bf2f(hv[u]), accf[u]);
        }
    }
#pragma unroll
    for (int o = 32; o; o >>= 1) wsum += __shfl_xor(wsum, o);
    // reduce feature partials across the 4 edge subgroups (lanes ^16, ^32)
#pragma unroll
    for (int u = 0; u < 8; u++) {
        accf[u] += __shfl_xor(accf[u], 16);
        accf[u] += __shfl_xor(accf[u], 32);
    }
    float inv = 1.f / (wsum + 1e-16f);
    if (eg == 0) {
        f32x4 o1 = {accf[0] * inv, accf[1] * inv, accf[2] * inv, accf[3] * inv};
        f32x4 o2 = {accf[4] * inv, accf[5] * inv, accf[6] * inv, accf[7] * inv};
        *(f32x4*)(out + (long)node * HH + f8) = o1;
        *(f32x4*)(out + (long)node * HH + f8 + 4) = o2;
    }
}

// ---------------- batchnorm ----------------
__global__ __launch_bounds__(256) void bnstats_k(const float* __restrict__ h,
                                                 float* __restrict__ bsum,
                                                 float* __restrict__ bsq, int n) {
    int col = threadIdx.x & 127;
    int half = threadIdx.x >> 7;
    int stride = gridDim.x * 2;
    float s = 0.f, sq = 0.f;
    for (int row = blockIdx.x * 2 + half; row < n; row += stride) {
        float v = h[(long)row * HH + col];
        s += v;
        sq += v * v;
    }
    atomicAdd(bsum + col, s);
    atomicAdd(bsq + col, sq);
}

__global__ __launch_bounds__(256) void bnapply_k(const float* __restrict__ h,
                                                 const float* __restrict__ bsum,
                                                 const float* __restrict__ bsq,
                                                 const float* __restrict__ g,
                                                 const float* __restrict__ b,
                                                 short* __restrict__ obf, int n) {
    long idx = (long)blockIdx.x * 256 + threadIdx.x;   // one float4 (4 cols) per thread
    long total = (long)n * 32;
    if (idx >= total) return;
    int col0 = ((int)(idx & 31)) * 4;
    float4 v = *(const float4*)(h + idx * 4);
    const float invn = 1.0f / (float)n;
    short4v o;
    float vv[4] = {v.x, v.y, v.z, v.w};
    short oo[4];
#pragma unroll
    for (int j = 0; j < 4; j++) {
        int c = col0 + j;
        float mu = bsum[c] * invn;
        float var = bsq[c] * invn - mu * mu;
        float rs = rsqrtf(var + 1e-5f);
        float val = (vv[j] - mu) * rs * g[c] + b[c];
        val = (val > 0.f) ? val : 0.2f * val;
        oo[j] = f2bf(val);
    }
    o.x = oo[0]; o.y = oo[1]; o.z = oo[2]; o.w = oo[3];
    *(short4v*)(obf + idx * 4) = o;
}

// ---------------- launch ----------------
extern "C" void kernel_launch(void* const* d_in, const int* in_sizes, int n_in,
                              void* d_out, int out_size, void* d_ws, size_t ws_size,
                              hipStream_t stream) {
    const float* x = (const float*)d_in[0];
    const int* ei = (const int*)d_in[1];
    const int* srcp = ei;
    const int* dstp = ei + EE;
    const float* W0 = (const float*)d_in[2];
    const float* as0 = (const float*)d_in[3];
    const float* ad0 = (const float*)d_in[4];
    const float* g0 = (const float*)d_in[5];
    const float* b0 = (const float*)d_in[6];
    const float* W1 = (const float*)d_in[7];
    const float* as1 = (const float*)d_in[8];
    const float* ad1 = (const float*)d_in[9];
    const float* g1 = (const float*)d_in[10];
    const float* b1 = (const float*)d_in[11];
    const float* locW = (const float*)d_in[12];
    const float* locb = (const float*)d_in[13];
    const float* stdW = (const float*)d_in[14];
    const float* stdb = (const float*)d_in[15];

    float* out = (float*)d_out;
    float* out_loc = out;
    float* out_std = out + (long)NN * OUTD;
    float* lvec = out + 2L * NN * OUTD;

    char* wsb = (char*)d_ws;
    size_t off = 0;
    auto alloc = [&](size_t bytes) {
        size_t cur = off;
        off += (bytes + 255) & ~(size_t)255;
        return cur;
    };
    short* h2bf = (short*)(wsb + alloc((size_t)NN * HH * 2));
    float* h_agg = (float*)(wsb + alloc((size_t)NN * HH * 4));
    short* ptrbf = (short*)(wsb + alloc((size_t)NN * HH * 2));
    int* col_src = (int*)(wsb + alloc((size_t)EE * 4));
    int* zreg = (int*)(wsb + alloc((size_t)(2 * NN + 256) * 4));  // counts|cursor|bn
    int* counts = zreg;
    int* cursor = zreg + NN;
    float* bn_sum = (float*)(zreg + 2 * NN);
    float* bn_sq = bn_sum + 128;
    int* row_ptr = (int*)(wsb + alloc((size_t)(NN + 1) * 4));
    float* alpha_s = (float*)(wsb + alloc((size_t)NN * 4));
    float* alpha_d = (float*)(wsb + alloc((size_t)NN * 4));
    short* W0T = (short*)(wsb + alloc((size_t)HH * FIN * 2));
    short* W1T = (short*)(wsb + alloc((size_t)HH * HH * 2));
    short* WHT = (short*)(wsb + alloc((size_t)HH * HH * 2));
    int* partials = (int*)(wsb + alloc(512));

    const int ZN = 2 * NN + 256;
    zero_k<<<(ZN + 255) / 256, 256, 0, stream>>>(zreg, ZN);
    convW0_k<<<(HH * FIN) / 256, 256, 0, stream>>>(W0, W0T);
    convW1_k<<<(HH * HH) / 256, 256, 0, stream>>>(W1, W1T);
    convWH_k<<<(HH * HH) / 256, 256, 0, stream>>>(locW, stdW, WHT);
    rowsum_k<<<NN, 256, 0, stream>>>(x, lvec);

    hist_k<<<(EE + 255) / 256, 256, 0, stream>>>(dstp, counts, EE);
    scanA_k<<<(NN + 1023) / 1024, 256, 0, stream>>>(counts, row_ptr, partials, NN);
    scanB_k<<<1, 128, 0, stream>>>(partials, (NN + 1023) / 1024);
    scanC_k<<<(NN + 255) / 256, 256, 0, stream>>>(row_ptr, partials, NN, EE);
    fill_k<<<(EE + 255) / 256, 256, 0, stream>>>(srcp, dstp, row_ptr, cursor, col_src, EE);

    const int GB = (NN + 127) / 128;   // 782 gemm blocks
    // ---- layer 0 ----
    gemm_k<0, 0><<<GB, 256, 0, stream>>>(x, lvec, W0T, h2bf, nullptr, nullptr, nullptr, nullptr, NN, FIN);
    alpha_k<<<(NN + 3) / 4, 256, 0, stream>>>(h2bf, as0, ad0, alpha_s, alpha_d, NN);
    agg_k<<<(NN + 3) / 4, 256, 0, stream>>>(h2bf, alpha_s, alpha_d, row_ptr, col_src, h_agg, NN);
    bnstats_k<<<256, 256, 0, stream>>>(h_agg, bn_sum, bn_sq, NN);
    bnapply_k<<<(NN * 32 + 255) / 256, 256, 0, stream>>>(h_agg, bn_sum, bn_sq, g0, b0, ptrbf, NN);
    zero_k<<<1, 256, 0, stream>>>((int*)bn_sum, 256);
    // ---- layer 1 ----
    gemm_k<1, 0><<<GB, 256, 0, stream>>>(ptrbf, nullptr, W1T, h2bf, nullptr, nullptr, nullptr, nullptr, NN, HH);
    alpha_k<<<(NN + 3) / 4, 256, 0, stream>>>(h2bf, as1, ad1, alpha_s, alpha_d, NN);
    agg_k<<<(NN + 3) / 4, 256, 0, stream>>>(h2bf, alpha_s, alpha_d, row_ptr, col_src, h_agg, NN);
    bnstats_k<<<256, 256, 0, stream>>>(h_agg, bn_sum, bn_sq, NN);
    bnapply_k<<<(NN * 32 + 255) / 256, 256, 0, stream>>>(h_agg, bn_sum, bn_sq, g1, b1, ptrbf, NN);
    // ---- head ----
    gemm_k<1, 1><<<GB, 256, 0, stream>>>(ptrbf, nullptr, WHT, nullptr, locb, stdb, out_loc, out_std, NN, HH);
}

// Round 3
// 1159.086 us; speedup vs baseline: 1.1496x; 1.0403x over previous
//
#include <hip/hip_runtime.h>

#define NN 100000
#define EE 1600000
#define FIN 1024
#define HH 128
#define OUTD 32
#define TOTC 10000.0f

typedef float f32x4 __attribute__((ext_vector_type(4)));
typedef short bf16x8 __attribute__((ext_vector_type(8)));
typedef short short4v __attribute__((ext_vector_type(4)));

static __device__ __forceinline__ short f2bf(float f) {
    unsigned u = __float_as_uint(f);
    unsigned r = (u + 0x7fffu + ((u >> 16) & 1u)) >> 16;
    return (short)r;
}
static __device__ __forceinline__ float bf2f(short s) {
    return __uint_as_float(((unsigned)(unsigned short)s) << 16);
}

// ---------------- small utility kernels ----------------
__global__ void zero_k(int* __restrict__ p, int n) {
    int i = blockIdx.x * 256 + threadIdx.x;
    if (i < n) p[i] = 0;
}

// row sums of x -> l (output #2), one block per row
__global__ __launch_bounds__(256) void rowsum_k(const float* __restrict__ x,
                                                float* __restrict__ lout) {
    int row = blockIdx.x;
    int tid = threadIdx.x;
    const float4* px = (const float4*)(x + (long)row * FIN);
    float4 v = px[tid];
    float s = v.x + v.y + v.z + v.w;
#pragma unroll
    for (int o = 32; o; o >>= 1) s += __shfl_xor(s, o);
    __shared__ float ws[4];
    if ((tid & 63) == 0) ws[tid >> 6] = s;
    __syncthreads();
    if (tid == 0) lout[row] = ws[0] + ws[1] + ws[2] + ws[3];
}

// weight conversions (bf16, transposed: BT[n][k] = W[k][n])
__global__ void convW0_k(const float* __restrict__ W, short* __restrict__ BT) {
    int idx = blockIdx.x * 256 + threadIdx.x;     // 128*1024
    int n = idx >> 10, k = idx & 1023;
    BT[idx] = f2bf(W[(long)k * HH + n]);
}
__global__ void convW1_k(const float* __restrict__ W, short* __restrict__ BT) {
    int idx = blockIdx.x * 256 + threadIdx.x;     // 128*128
    int n = idx >> 7, k = idx & 127;
    BT[idx] = f2bf(W[k * HH + n]);
}
__global__ void convWH_k(const float* __restrict__ locW, const float* __restrict__ stdW,
                         short* __restrict__ BT) {
    int idx = blockIdx.x * 256 + threadIdx.x;     // 128*128
    int n = idx >> 7, k = idx & 127;
    float v = (n < 32) ? locW[k * OUTD + n] : ((n < 64) ? stdW[k * OUTD + (n - 32)] : 0.0f);
    BT[idx] = f2bf(v);
}

// ---------------- CSR build ----------------
__global__ void hist_k(const int* __restrict__ dst, int* __restrict__ cnt, int e) {
    int i = blockIdx.x * 256 + threadIdx.x;
    if (i < e) atomicAdd(cnt + dst[i], 1);
}

__global__ __launch_bounds__(256) void scanA_k(const int* __restrict__ cnt,
                                               int* __restrict__ out,
                                               int* __restrict__ partials, int n) {
    __shared__ int sc[256];
    int tid = threadIdx.x;
    int base = blockIdx.x * 1024 + tid * 4;
    int c[4];
#pragma unroll
    for (int u = 0; u < 4; u++) c[u] = (base + u < n) ? cnt[base + u] : 0;
    int s = c[0] + c[1] + c[2] + c[3];
    sc[tid] = s;
    __syncthreads();
    for (int of = 1; of < 256; of <<= 1) {
        int v = (tid >= of) ? sc[tid - of] : 0;
        __syncthreads();
        sc[tid] += v;
        __syncthreads();
    }
    int e = sc[tid] - s;
#pragma unroll
    for (int u = 0; u < 4; u++) {
        if (base + u < n) out[base + u] = e;
        e += c[u];
    }
    if (tid == 255) partials[blockIdx.x] = sc[255];
}

__global__ __launch_bounds__(128) void scanB_k(int* __restrict__ partials, int nblk) {
    __shared__ int sc[128];
    int tid = threadIdx.x;
    int v = (tid < nblk) ? partials[tid] : 0;
    sc[tid] = v;
    __syncthreads();
    for (int of = 1; of < 128; of <<= 1) {
        int t2 = (tid >= of) ? sc[tid - of] : 0;
        __syncthreads();
        sc[tid] += t2;
        __syncthreads();
    }
    if (tid < nblk) partials[tid] = sc[tid] - v;   // exclusive block offsets
}

__global__ void scanC_k(int* __restrict__ rp, const int* __restrict__ offs, int n, int total) {
    int i = blockIdx.x * 256 + threadIdx.x;
    if (i < n) rp[i] += offs[i >> 10];
    if (i == 0) rp[n] = total;
}

__global__ void fill_k(const int* __restrict__ src, const int* __restrict__ dst,
                       const int* __restrict__ rp, int* __restrict__ cur,
                       int* __restrict__ cs, int e) {
    int i = blockIdx.x * 256 + threadIdx.x;
    if (i < e) {
        int d = dst[i];
        int p = atomicAdd(cur + d, 1);
        cs[rp[d] + p] = src[i];
    }
}

// ---------------- bf16 MFMA GEMM: C[M,128] = A[M,K] @ B[K,128] ----------------
// ASRC: 0 = A is fp32 x with fused log1p(x * TOTC/l[row])
//       2 = A is fp32 h_agg with fused batchnorm (from bn stats) + leaky_relu
// EPI:  0 = store bf16 C; 1 = head epilogue (loc + softplus(std))
#define LDP 88   // padded LDS row stride in bf16 elems (176 B, 16B-divisible)

template <int ASRC, int EPI>
__global__ __launch_bounds__(256) void gemm_k(
    const void* __restrict__ Ap, const float* __restrict__ lvec,
    const float* __restrict__ bnsum, const float* __restrict__ bnsq,
    const float* __restrict__ gv, const float* __restrict__ bv,
    const short* __restrict__ BT, short* __restrict__ Cbf,
    const float* __restrict__ bias_loc, const float* __restrict__ bias_std,
    float* __restrict__ out_loc, float* __restrict__ out_std, int M, int K) {
    __shared__ short sA[128 * LDP];
    __shared__ short sB[128 * LDP];
    __shared__ float sScale[128];
    __shared__ float sShift[128];
    const int tid = threadIdx.x;
    const int row0 = blockIdx.x * 128;
    if (ASRC == 0) {
        if (tid < 128) {
            int g = row0 + tid;
            sScale[tid] = (g < M) ? (TOTC / lvec[g]) : 0.0f;
        }
    } else {
        if (tid < 128) {
            const float invn = 1.0f / (float)M;
            float mu = bnsum[tid] * invn;
            float var = bnsq[tid] * invn - mu * mu;
            float grs = gv[tid] * rsqrtf(var + 1e-5f);
            sScale[tid] = grs;
            sShift[tid] = bv[tid] - mu * grs;
        }
    }
    __syncthreads();

    const int lane = tid & 63;
    const int wv = tid >> 6;
    const int wm = (wv & 1) * 64, wn = (wv >> 1) * 64;
    const int lm = lane & 15, q = lane >> 4;

    f32x4 acc[4][4];
#pragma unroll
    for (int i = 0; i < 4; i++)
#pragma unroll
        for (int j = 0; j < 4; j++) acc[i][j] = {0.f, 0.f, 0.f, 0.f};

    const int r = tid >> 1;            // 0..127 (tile row / B col)
    const int cb = (tid & 1) * 32;     // k-chunk base within BK=64
    const int gr = row0 + r;

    for (int kk = 0; kk < K; kk += 64) {
        // ---- stage A tile [128 x 64] ----
        if (gr < M) {
            const float* X = (const float*)Ap;
            const float4* px = (const float4*)(X + (long)gr * K + kk + cb);
            if (ASRC == 0) {
                const float s = sScale[r];
#pragma unroll
                for (int u = 0; u < 8; ++u) {
                    float4 v = px[u];
                    short4v o;
                    o.x = f2bf(__logf(fmaf(v.x, s, 1.0f)));
                    o.y = f2bf(__logf(fmaf(v.y, s, 1.0f)));
                    o.z = f2bf(__logf(fmaf(v.z, s, 1.0f)));
                    o.w = f2bf(__logf(fmaf(v.w, s, 1.0f)));
                    *(short4v*)&sA[r * LDP + cb + u * 4] = o;
                }
            } else {
#pragma unroll
                for (int u = 0; u < 8; ++u) {
                    float4 v = px[u];
                    int c = kk + cb + u * 4;
                    float vv[4] = {v.x, v.y, v.z, v.w};
                    short oo[4];
#pragma unroll
                    for (int t = 0; t < 4; t++) {
                        float val = fmaf(vv[t], sScale[c + t], sShift[c + t]);
                        val = (val > 0.f) ? val : 0.2f * val;
                        oo[t] = f2bf(val);
                    }
                    short4v o;
                    o.x = oo[0]; o.y = oo[1]; o.z = oo[2]; o.w = oo[3];
                    *(short4v*)&sA[r * LDP + cb + u * 4] = o;
                }
            }
        } else {
            short4v z;
            z.x = z.y = z.z = z.w = 0;
#pragma unroll
            for (int u = 0; u < 8; ++u) *(short4v*)&sA[r * LDP + cb + u * 4] = z;
        }
        // ---- stage B tile: sB[n][k] from BT[n][K] ----
        {
            const short4v* pb = (const short4v*)(BT + (long)r * K + kk + cb);
#pragma unroll
            for (int u = 0; u < 8; ++u) *(short4v*)&sB[r * LDP + cb + u * 4] = pb[u];
        }
        __syncthreads();
        // ---- MFMA: 2 k-steps of 32 ----
#pragma unroll
        for (int ks = 0; ks < 64; ks += 32) {
            bf16x8 af[4], bf[4];
#pragma unroll
            for (int i = 0; i < 4; i++)
                af[i] = *(const bf16x8*)&sA[(wm + i * 16 + lm) * LDP + ks + q * 8];
#pragma unroll
            for (int j = 0; j < 4; j++)
                bf[j] = *(const bf16x8*)&sB[(wn + j * 16 + lm) * LDP + ks + q * 8];
#pragma unroll
            for (int i = 0; i < 4; i++)
#pragma unroll
                for (int j = 0; j < 4; j++)
                    acc[i][j] = __builtin_amdgcn_mfma_f32_16x16x32_bf16(af[i], bf[j], acc[i][j], 0, 0, 0);
        }
        __syncthreads();
    }

    // ---- epilogue ----
    if (EPI == 0) {
#pragma unroll
        for (int i = 0; i < 4; i++)
#pragma unroll
            for (int rg = 0; rg < 4; rg++) {
                int grow = row0 + wm + i * 16 + q * 4 + rg;
                if (grow < M) {
#pragma unroll
                    for (int j = 0; j < 4; j++) {
                        int col = wn + j * 16 + lm;
                        Cbf[(long)grow * HH + col] = f2bf(acc[i][j][rg]);
                    }
                }
            }
    } else {
        if (wn == 0) {
#pragma unroll
            for (int i = 0; i < 4; i++)
#pragma unroll
                for (int rg = 0; rg < 4; rg++) {
                    int grow = row0 + wm + i * 16 + q * 4 + rg;
                    if (grow < M) {
#pragma unroll
                        for (int j = 0; j < 4; j++) {
                            int col = j * 16 + lm;   // 0..63
                            float v = acc[i][j][rg];
                            if (col < 32) {
                                out_loc[(long)grow * OUTD + col] = v + bias_loc[col];
                            } else {
                                float xv = v + bias_std[col - 32];
                                float sp = fmaxf(xv, 0.f) + __logf(1.f + __expf(-fabsf(xv)));
                                out_std[(long)grow * OUTD + (col - 32)] = sp + 1e-7f;
                            }
                        }
                    }
                }
        }
    }
}

// ---------------- alpha: per-row dots with a_s / a_d (bf16 h2) ----------------
__global__ __launch_bounds__(256) void alpha_k(const short* __restrict__ h2bf,
                                               const float* __restrict__ avs,
                                               const float* __restrict__ avd,
                                               float* __restrict__ outs,
                                               float* __restrict__ outd, int n) {
    int lane = threadIdx.x & 63;
    int row = blockIdx.x * 4 + (threadIdx.x >> 6);
    if (row >= n) return;
    unsigned pv = *(const unsigned*)(h2bf + (long)row * HH + 2 * lane);
    float v0 = __uint_as_float((pv & 0xffffu) << 16);
    float v1 = __uint_as_float(pv & 0xffff0000u);
    float ps = v0 * avs[2 * lane] + v1 * avs[2 * lane + 1];
    float pd = v0 * avd[2 * lane] + v1 * avd[2 * lane + 1];
#pragma unroll
    for (int o = 32; o; o >>= 1) {
        ps += __shfl_xor(ps, o);
        pd += __shfl_xor(pd, o);
    }
    if (lane == 0) {
        outs[row] = ps;
        outd[row] = pd;
    }
}

// ---------------- GAT aggregation: one wave per dst node ----------------
// No max pass (exp(e-m)/sum cancels m exactly); 4-edge batches with 4-deep MLP.
__global__ __launch_bounds__(256) void agg_k(const short* __restrict__ h2bf,
                                             const float* __restrict__ as,
                                             const float* __restrict__ ad,
                                             const int* __restrict__ row_ptr,
                                             const int* __restrict__ col_src,
                                             float* __restrict__ out, int n) {
    int lane = threadIdx.x & 63;
    int node = blockIdx.x * 4 + (threadIdx.x >> 6);
    if (node >= n) return;
    int s0 = row_ptr[node], s1 = row_ptr[node + 1];
    float adv = ad[node];

    const int eg = lane >> 4;        // edge subgroup 0..3
    const int f8 = (lane & 15) * 8;  // feature octet offset
    float accf[8];
#pragma unroll
    for (int u = 0; u < 8; u++) accf[u] = 0.f;
    float wsum = 0.f;

    for (int b = s0; b < s1; b += 64) {
        int idx = b + lane;
        float w = 0.f;
        int s = 0;
        if (idx < s1) {
            s = col_src[idx];
            float e = as[s] + adv;
            e = (e > 0.f) ? e : 0.2f * e;
            w = __expf(e);
            wsum += w;
        }
        int cl = min(64, s1 - b);
        for (int jb0 = 0; jb0 < cl; jb0 += 16) {
            float wj[4];
            const bf16x8* p[4];
#pragma unroll
            for (int t = 0; t < 4; t++) {
                int j = jb0 + t * 4 + eg;
                wj[t] = __shfl(w, j);
                int sj = __shfl(s, j);
                p[t] = (const bf16x8*)(h2bf + (long)sj * HH + f8);
            }
            bool a1 = (jb0 + 4) < cl, a2 = (jb0 + 8) < cl, a3 = (jb0 + 12) < cl;
            bf16x8 hv0, hv1, hv2, hv3;
            hv0 = *p[0];
            if (a1) hv1 = *p[1];
            if (a2) hv2 = *p[2];
            if (a3) hv3 = *p[3];
#pragma unroll
            for (int u = 0; u < 8; u++) accf[u] = fmaf(wj[0], bf2f(hv0[u]), accf[u]);
            if (a1) {
#pragma unroll
                for (int u = 0; u < 8; u++) accf[u] = fmaf(wj[1], bf2f(hv1[u]), accf[u]);
            }
            if (a2) {
#pragma unroll
                for (int u = 0; u < 8; u++) accf[u] = fmaf(wj[2], bf2f(hv2[u]), accf[u]);
            }
            if (a3) {
#pragma unroll
                for (int u = 0; u < 8; u++) accf[u] = fmaf(wj[3], bf2f(hv3[u]), accf[u]);
            }
        }
    }
#pragma unroll
    for (int o = 32; o; o >>= 1) wsum += __shfl_xor(wsum, o);
    // reduce feature partials across the 4 edge subgroups (lanes ^16, ^32)
#pragma unroll
    for (int u = 0; u < 8; u++) {
        accf[u] += __shfl_xor(accf[u], 16);
        accf[u] += __shfl_xor(accf[u], 32);
    }
    float inv = 1.f / (wsum + 1e-16f);
    if (eg == 0) {
        f32x4 o1 = {accf[0] * inv, accf[1] * inv, accf[2] * inv, accf[3] * inv};
        f32x4 o2 = {accf[4] * inv, accf[5] * inv, accf[6] * inv, accf[7] * inv};
        *(f32x4*)(out + (long)node * HH + f8) = o1;
        *(f32x4*)(out + (long)node * HH + f8 + 4) = o2;
    }
}

// ---------------- batchnorm stats ----------------
__global__ __launch_bounds__(256) void bnstats_k(const float* __restrict__ h,
                                                 float* __restrict__ bsum,
                                                 float* __restrict__ bsq, int n) {
    int col = threadIdx.x & 127;
    int half = threadIdx.x >> 7;
    int stride = gridDim.x * 2;
    float s = 0.f, sq = 0.f;
    for (int row = blockIdx.x * 2 + half; row < n; row += stride) {
        float v = h[(long)row * HH + col];
        s += v;
        sq += v * v;
    }
    atomicAdd(bsum + col, s);
    atomicAdd(bsq + col, sq);
}

// ---------------- launch ----------------
extern "C" void kernel_launch(void* const* d_in, const int* in_sizes, int n_in,
                              void* d_out, int out_size, void* d_ws, size_t ws_size,
                              hipStream_t stream) {
    const float* x = (const float*)d_in[0];
    const int* ei = (const int*)d_in[1];
    const int* srcp = ei;
    const int* dstp = ei + EE;
    const float* W0 = (const float*)d_in[2];
    const float* as0 = (const float*)d_in[3];
    const float* ad0 = (const float*)d_in[4];
    const float* g0 = (const float*)d_in[5];
    const float* b0 = (const float*)d_in[6];
    const float* W1 = (const float*)d_in[7];
    const float* as1 = (const float*)d_in[8];
    const float* ad1 = (const float*)d_in[9];
    const float* g1 = (const float*)d_in[10];
    const float* b1 = (const float*)d_in[11];
    const float* locW = (const float*)d_in[12];
    const float* locb = (const float*)d_in[13];
    const float* stdW = (const float*)d_in[14];
    const float* stdb = (const float*)d_in[15];

    float* out = (float*)d_out;
    float* out_loc = out;
    float* out_std = out + (long)NN * OUTD;
    float* lvec = out + 2L * NN * OUTD;

    char* wsb = (char*)d_ws;
    size_t off = 0;
    auto alloc = [&](size_t bytes) {
        size_t cur = off;
        off += (bytes + 255) & ~(size_t)255;
        return cur;
    };
    short* h2bf = (short*)(wsb + alloc((size_t)NN * HH * 2));
    float* h_agg = (float*)(wsb + alloc((size_t)NN * HH * 4));
    int* col_src = (int*)(wsb + alloc((size_t)EE * 4));
    int* zreg = (int*)(wsb + alloc((size_t)(2 * NN + 256) * 4));  // counts|cursor|bn
    int* counts = zreg;
    int* cursor = zreg + NN;
    float* bn_sum = (float*)(zreg + 2 * NN);
    float* bn_sq = bn_sum + 128;
    int* row_ptr = (int*)(wsb + alloc((size_t)(NN + 1) * 4));
    float* alpha_s = (float*)(wsb + alloc((size_t)NN * 4));
    float* alpha_d = (float*)(wsb + alloc((size_t)NN * 4));
    short* W0T = (short*)(wsb + alloc((size_t)HH * FIN * 2));
    short* W1T = (short*)(wsb + alloc((size_t)HH * HH * 2));
    short* WHT = (short*)(wsb + alloc((size_t)HH * HH * 2));
    int* partials = (int*)(wsb + alloc(512));

    const int ZN = 2 * NN + 256;
    zero_k<<<(ZN + 255) / 256, 256, 0, stream>>>(zreg, ZN);
    convW0_k<<<(HH * FIN) / 256, 256, 0, stream>>>(W0, W0T);
    convW1_k<<<(HH * HH) / 256, 256, 0, stream>>>(W1, W1T);
    convWH_k<<<(HH * HH) / 256, 256, 0, stream>>>(locW, stdW, WHT);
    rowsum_k<<<NN, 256, 0, stream>>>(x, lvec);

    hist_k<<<(EE + 255) / 256, 256, 0, stream>>>(dstp, counts, EE);
    scanA_k<<<(NN + 1023) / 1024, 256, 0, stream>>>(counts, row_ptr, partials, NN);
    scanB_k<<<1, 128, 0, stream>>>(partials, (NN + 1023) / 1024);
    scanC_k<<<(NN + 255) / 256, 256, 0, stream>>>(row_ptr, partials, NN, EE);
    fill_k<<<(EE + 255) / 256, 256, 0, stream>>>(srcp, dstp, row_ptr, cursor, col_src, EE);

    const int GB = (NN + 127) / 128;   // 782 gemm blocks
    // ---- layer 0 ----
    gemm_k<0, 0><<<GB, 256, 0, stream>>>(x, lvec, nullptr, nullptr, nullptr, nullptr,
                                         W0T, h2bf, nullptr, nullptr, nullptr, nullptr, NN, FIN);
    alpha_k<<<(NN + 3) / 4, 256, 0, stream>>>(h2bf, as0, ad0, alpha_s, alpha_d, NN);
    agg_k<<<(NN + 3) / 4, 256, 0, stream>>>(h2bf, alpha_s, alpha_d, row_ptr, col_src, h_agg, NN);
    bnstats_k<<<256, 256, 0, stream>>>(h_agg, bn_sum, bn_sq, NN);
    // ---- layer 1 (BN0+lrelu fused into A-staging) ----
    gemm_k<2, 0><<<GB, 256, 0, stream>>>(h_agg, nullptr, bn_sum, bn_sq, g0, b0,
                                         W1T, h2bf, nullptr, nullptr, nullptr, nullptr, NN, HH);
    alpha_k<<<(NN + 3) / 4, 256, 0, stream>>>(h2bf, as1, ad1, alpha_s, alpha_d, NN);
    zero_k<<<1, 256, 0, stream>>>((int*)bn_sum, 256);
    agg_k<<<(NN + 3) / 4, 256, 0, stream>>>(h2bf, alpha_s, alpha_d, row_ptr, col_src, h_agg, NN);
    bnstats_k<<<256, 256, 0, stream>>>(h_agg, bn_sum, bn_sq, NN);
    // ---- head (BN1+lrelu fused into A-staging) ----
    gemm_k<2, 1><<<GB, 256, 0, stream>>>(h_agg, nullptr, bn_sum, bn_sq, g1, b1,
                                         WHT, nullptr, locb, stdb, out_loc, out_std, NN, HH);
}